// Round 1
// baseline (136.395 us; speedup 1.0000x reference)
//
#include <hip/hip_runtime.h>
#include <hip/hip_bf16.h>
#include <math.h>

#define KMIX 16
#define DIM  16
#define TRI  136   // 16*17/2 packed lower-triangular size

// ---------------------------------------------------------------------------
// Precompute (1 block, 256 threads = K*D):
//   Cholesky Sigma_k = L L^T  (in LDS, thread (k,i) owns row i)
//   Linv = L^{-1}             (thread (k,c) solves column c)
//   wsL: packed rows of Linv  [K][136]
//   wsB: b_k = Linv * mu_k    [K][16]
//   wsC: Phi_k / sqrt(2*pi*det(Sigma_k))   [K]
// ---------------------------------------------------------------------------
__global__ __launch_bounds__(256) void gmm_precompute(
    const float* __restrict__ Phi, const float* __restrict__ mu,
    const float* __restrict__ Sigma,
    float* __restrict__ wsL, float* __restrict__ wsB, float* __restrict__ wsC)
{
    __shared__ float A[KMIX][DIM][DIM + 1];
    __shared__ float Li[KMIX][DIM][DIM];
    const int t = threadIdx.x;
    const int k = t >> 4;
    const int i = t & 15;

    for (int j = 0; j < DIM; ++j) A[k][i][j] = Sigma[(k * DIM + i) * DIM + j];
    __syncthreads();

    // Right-looking Cholesky (lower triangle), 16 steps.
    for (int j = 0; j < DIM; ++j) {
        if (i == j) A[k][j][j] = sqrtf(A[k][j][j]);
        __syncthreads();
        if (i > j) A[k][i][j] /= A[k][j][j];
        __syncthreads();
        if (i > j) {
            const float lij = A[k][i][j];
            for (int m = j + 1; m <= i; ++m) A[k][i][m] -= lij * A[k][m][j];
        }
        __syncthreads();
    }

    // Forward-substitution: solve L y = e_c  (thread's column c = i)
    {
        const int c = i;
        float y[DIM];
        #pragma unroll
        for (int r = 0; r < DIM; ++r) {
            float s = (r == c) ? 1.0f : 0.0f;
            #pragma unroll
            for (int m = 0; m < DIM; ++m) {
                if (m < r) {
                    // only m >= c entries of y are nonzero; cheap runtime guard
                    s -= (m >= c) ? A[k][r][m] * y[m] : 0.0f;
                }
            }
            y[r] = (r < c) ? 0.0f : s / A[k][r][r];
        }
        #pragma unroll
        for (int r = 0; r < DIM; ++r) Li[k][r][c] = y[r];
    }
    __syncthreads();

    if (i == 0) {
        float det = 1.0f;
        for (int j = 0; j < DIM; ++j) { const float d = A[k][j][j]; det *= d * d; }
        wsC[k] = Phi[k] / sqrtf(2.0f * 3.14159265358979323846f * det);
    }

    float b = 0.0f;
    for (int j = 0; j <= i; ++j) b += Li[k][i][j] * mu[k * DIM + j];
    wsB[k * DIM + i] = b;
    for (int j = 0; j <= i; ++j)
        wsL[k * TRI + (i * (i + 1)) / 2 + j] = Li[k][i][j];
}

// ---------------------------------------------------------------------------
// Main: one thread per sample. quad_k = || Linv_k * x - b_k ||^2.
// Matrix/vector constants are wave-uniform -> scalar loads (s_load), so the
// VALU sees only the 136+16 FMA per mixture.
// ---------------------------------------------------------------------------
__global__ __launch_bounds__(256) void gmm_main(
    const float* __restrict__ samples,
    const float* __restrict__ wsL, const float* __restrict__ wsB,
    const float* __restrict__ wsC, float* __restrict__ out, int N)
{
    const int n = blockIdx.x * 256 + threadIdx.x;
    if (n >= N) return;

    const float4* x4 = (const float4*)samples + (size_t)n * 4;
    const float4 v0 = x4[0], v1 = x4[1], v2 = x4[2], v3 = x4[3];
    const float x[DIM] = {v0.x, v0.y, v0.z, v0.w, v1.x, v1.y, v1.z, v1.w,
                          v2.x, v2.y, v2.z, v2.w, v3.x, v3.y, v3.z, v3.w};

    float sum = 0.0f;
    for (int k = 0; k < KMIX; ++k) {
        const float* __restrict__ Lk = wsL + k * TRI;
        const float* __restrict__ bk = wsB + k * DIM;
        float q = 0.0f;
        #pragma unroll
        for (int i = 0; i < DIM; ++i) {
            float yv = -bk[i];
            const float* row = Lk + (i * (i + 1)) / 2;
            #pragma unroll
            for (int j = 0; j <= i; ++j) yv = fmaf(row[j], x[j], yv);
            q = fmaf(yv, yv, q);
        }
        sum += wsC[k] * __expf(-0.5f * q);
    }
    out[n] = -__logf(sum);
}

extern "C" void kernel_launch(void* const* d_in, const int* in_sizes, int n_in,
                              void* d_out, int out_size, void* d_ws, size_t ws_size,
                              hipStream_t stream)
{
    const float* samples = (const float*)d_in[0];
    const float* Phi     = (const float*)d_in[1];
    const float* mu      = (const float*)d_in[2];
    const float* Sigma   = (const float*)d_in[3];
    float* out = (float*)d_out;
    const int N = in_sizes[0] / DIM;

    float* wsL = (float*)d_ws;          // K*136 floats
    float* wsB = wsL + KMIX * TRI;      // K*16
    float* wsC = wsB + KMIX * DIM;      // K

    gmm_precompute<<<1, 256, 0, stream>>>(Phi, mu, Sigma, wsL, wsB, wsC);
    gmm_main<<<(N + 255) / 256, 256, 0, stream>>>(samples, wsL, wsB, wsC, out, N);
}